// Round 4
// baseline (167.409 us; speedup 1.0000x reference)
//
#include <hip/hip_runtime.h>
#include <hip/hip_bf16.h>
#include <stdint.h>

// B=32, S=4096, ENC=512, DEC=512
// out = softmax_s( sum_d tanh( enc @ W_e^T + dh @ W_h^T + b ) * v )

typedef __attribute__((ext_vector_type(8))) short short8;
typedef __attribute__((ext_vector_type(4))) float f32x4;

static __device__ __forceinline__ unsigned short f2bf(float f) {
    union { float f; uint32_t u; } x{f};
    uint32_t u = x.u;
    u += 0x7fffu + ((u >> 16) & 1u);   // RNE
    return (unsigned short)(u >> 16);
}

static __device__ __forceinline__ float tanh_fast(float x) {
    // tanh(x) = 1 - 2/(exp(2x)+1); overflow->+1, underflow->-1 (both correct)
    return 1.0f - 2.0f / (__expf(2.0f * x) + 1.0f);
}

// ---------------------------------------------------------------------------
// Kernel 1 (96 blocks x 512):
//   blocks 0..63 : W_e (= W_attn[:,512:]) -> bf16, K-tiled [kt][n(512)][64],
//                  128B rows, 16B-group XOR swizzle (^ (n&7)<<4) so the main
//                  kernel stages linearly via global_load_lds.
//   blocks 64..95: proj1[b][e] = sum_d dh[b,d]*W_attn[e,d] + b_attn[e]
// ---------------------------------------------------------------------------
__global__ __launch_bounds__(512) void prep_kernel(
    const float* __restrict__ dh, const float* __restrict__ W_attn,
    const float* __restrict__ b_attn, unsigned short* __restrict__ wsB,
    float* __restrict__ wsP1) {
    __shared__ float dhs[512];
    const int tid = threadIdx.x;
    if (blockIdx.x < 64) {
        int idx = blockIdx.x * 512 + tid;      // 0..32767
        int c8 = idx & 7;                       // 16B group in row
        int n  = (idx >> 3) & 511;              // W_e row (output dim d)
        int kt = idx >> 12;                     // K tile 0..7
        const float* src = W_attn + (size_t)n * 1024 + 512 + kt * 64 + c8 * 8;
        float4 f0 = *(const float4*)(src);
        float4 f1 = *(const float4*)(src + 4);
        short8 p;
        p[0] = (short)f2bf(f0.x); p[1] = (short)f2bf(f0.y);
        p[2] = (short)f2bf(f0.z); p[3] = (short)f2bf(f0.w);
        p[4] = (short)f2bf(f1.x); p[5] = (short)f2bf(f1.y);
        p[6] = (short)f2bf(f1.z); p[7] = (short)f2bf(f1.w);
        int row = kt * 512 + n;
        int byteInRow = (c8 * 16) ^ ((n & 7) << 4);
        *(short8*)((char*)wsB + (size_t)row * 128 + byteInRow) = p;
    } else {
        int b = blockIdx.x - 64;
        dhs[tid] = dh[b * 512 + tid];
        __syncthreads();
        const float* wrow = W_attn + (size_t)tid * 1024;  // W_h row e=tid
        float acc = 0.f;
        #pragma unroll 8
        for (int d = 0; d < 512; d += 4) {
            float4 w = *(const float4*)(wrow + d);
            acc += dhs[d] * w.x + dhs[d + 1] * w.y + dhs[d + 2] * w.z + dhs[d + 3] * w.w;
        }
        wsP1[b * 512 + tid] = acc + b_attn[tid];
    }
}

// ---------------------------------------------------------------------------
// Kernel 2: fused GEMM (128 rows x 512 cols per block, K=512) + tanh + v-dot.
// 8 waves 2Mx4N, wave tile 64x128 (4x8 frags of 16x16x32 bf16 MFMA).
// LDS 160KB: A 2x16KB + B 2x64KB, double-buffered.
// T4 counted-vmcnt pipeline: raw s_barrier, stage kt+1/kt+2 loads stay in
// flight ACROSS barriers; vmcnt never drained to 0 in steady state.
// Per-wave vm-op ledger per stage: A-reg loads = 4, B global_load_lds = 8.
// ---------------------------------------------------------------------------
__global__ __launch_bounds__(512, 2) void fused_kernel(
    const float* __restrict__ enc, const unsigned short* __restrict__ wsB,
    const float* __restrict__ wsP1, const float* __restrict__ vvec,
    float* __restrict__ out) {
    __shared__ char lds[163840];
    char* const Ab0 = lds;            // [128][128B] bf16 swz
    char* const Ab1 = lds + 16384;
    char* const Bb0 = lds + 32768;    // [512][128B] bf16 swz
    char* const Bb1 = lds + 98304;

    const int tid  = threadIdx.x;
    const int wave = tid >> 6;
    const int lane = tid & 63;
    const int llo  = lane & 15, lhi = lane >> 4;
    const int wr   = wave >> 2, wc = wave & 3;

    // XCD-chunked bijective swizzle (1024 % 8 == 0)
    const int bid = blockIdx.x;
    const int lb  = (bid & 7) * 128 + (bid >> 3);
    const int m0  = lb * 128;
    const int b   = m0 >> 12;                    // batch (128 | 4096)

    // A staging map: thread -> (row ar, 16-f32 K chunk ac)
    const int ar = tid >> 2, ac = tid & 3;
    const float* aptr = enc + (size_t)(m0 + ar) * 512 + ac * 16;
    const int aoff0 = ar * 128 + (((ac * 32)     ) ^ ((ar & 7) << 4));
    const int aoff1 = ar * 128 + (((ac * 32) + 16) ^ ((ar & 7) << 4));

    f32x4 acc[4][8] = {};
    float4 fa0, fa1, fa2, fa3;

    #define FENCE() asm volatile("" ::: "memory")
    #define SCHEDB() __builtin_amdgcn_sched_barrier(0)
    #define BAR() __builtin_amdgcn_s_barrier()

    #define A_LOAD(kt)                                 \
        do { const float* p_ = aptr + (kt) * 64;       \
             fa0 = *(const float4*)(p_);               \
             fa1 = *(const float4*)(p_ + 4);           \
             fa2 = *(const float4*)(p_ + 8);           \
             fa3 = *(const float4*)(p_ + 12); } while (0)

    #define A_WRITE(Adst)                                                \
        do { short8 p0_, p1_;                                            \
             p0_[0]=(short)f2bf(fa0.x); p0_[1]=(short)f2bf(fa0.y);       \
             p0_[2]=(short)f2bf(fa0.z); p0_[3]=(short)f2bf(fa0.w);       \
             p0_[4]=(short)f2bf(fa1.x); p0_[5]=(short)f2bf(fa1.y);       \
             p0_[6]=(short)f2bf(fa1.z); p0_[7]=(short)f2bf(fa1.w);       \
             p1_[0]=(short)f2bf(fa2.x); p1_[1]=(short)f2bf(fa2.y);       \
             p1_[2]=(short)f2bf(fa2.z); p1_[3]=(short)f2bf(fa2.w);       \
             p1_[4]=(short)f2bf(fa3.x); p1_[5]=(short)f2bf(fa3.y);       \
             p1_[6]=(short)f2bf(fa3.z); p1_[7]=(short)f2bf(fa3.w);       \
             *(short8*)((Adst) + aoff0) = p0_;                           \
             *(short8*)((Adst) + aoff1) = p1_; } while (0)

    #define B_GLDS(kt, Bdst)                                                       \
        do { const char* bsrc_ = (const char*)wsB + (size_t)(kt) * 65536;          \
             _Pragma("unroll")                                                     \
             for (int i_ = 0; i_ < 8; ++i_) {                                      \
                 int off_ = (i_ * 8 + wave) * 1024;                                \
                 __builtin_amdgcn_global_load_lds(                                 \
                     (const uint32_t __attribute__((address_space(1)))*)(bsrc_ + off_ + lane * 16), \
                     (uint32_t __attribute__((address_space(3)))*)((Bdst) + off_), \
                     16, 0, 0);                                                    \
             } } while (0)

    #define COMPUTE(Asrc, Bsrc)                                                    \
        do { _Pragma("unroll")                                                     \
             for (int kk = 0; kk < 2; ++kk) {                                      \
                 const int gbyte = kk * 64 + lhi * 16;                             \
                 short8 af[4], bfr[8];                                             \
                 _Pragma("unroll")                                                 \
                 for (int mi = 0; mi < 4; ++mi) {                                  \
                     int row = wr * 64 + mi * 16 + llo;                            \
                     af[mi] = *(const short8*)((Asrc) + row * 128 +                \
                                               (gbyte ^ ((row & 7) << 4)));        \
                 }                                                                 \
                 _Pragma("unroll")                                                 \
                 for (int ni = 0; ni < 8; ++ni) {                                  \
                     int n = wc * 128 + ni * 16 + llo;                             \
                     bfr[ni] = *(const short8*)((Bsrc) + n * 128 +                 \
                                                (gbyte ^ ((n & 7) << 4)));         \
                 }                                                                 \
                 _Pragma("unroll")                                                 \
                 for (int mi = 0; mi < 4; ++mi)                                    \
                     _Pragma("unroll")                                             \
                     for (int ni = 0; ni < 8; ++ni)                                \
                         acc[mi][ni] = __builtin_amdgcn_mfma_f32_16x16x32_bf16(    \
                             af[mi], bfr[ni], acc[mi][ni], 0, 0, 0);               \
             } } while (0)

    // ---- prologue: stage 0 and issue stage 1 ----
    A_LOAD(0);                                  // vm: A0[4]
    FENCE();
    B_GLDS(0, Bb0);                             // vm: +B0[8] = 12
    asm volatile("s_waitcnt vmcnt(8)" ::: "memory");   // A0 landed
    SCHEDB();
    A_WRITE(Ab0);
    FENCE();
    A_LOAD(1);                                  // vm: B0[8]+A1[4] = 12
    FENCE();
    B_GLDS(1, Bb1);                             // vm: +B1[8] = 20
    asm volatile("s_waitcnt vmcnt(12) lgkmcnt(0)" ::: "memory"); // B0 + A-writes done
    SCHEDB(); BAR(); SCHEDB();                  // stage 0 published

    // ---- main loop, fully unrolled; per-wave vm ledger in comments ----
    // entering ITER(K): outstanding = A(K+1)[4] + B(K+1)[8] = 12
    #define ITER_MAIN(K, AcurS, AnxtS, BcurS, BnxtS)                               \
        do {                                                                       \
            asm volatile("s_waitcnt vmcnt(8)" ::: "memory");  /* A(K+1) landed */  \
            SCHEDB();                                                              \
            COMPUTE(AcurS, BcurS);                                                 \
            A_WRITE(AnxtS);                      /* stage K+1 A into other buf */  \
            SCHEDB(); BAR(); SCHEDB();           /* all waves done reading cur */  \
            A_LOAD((K) + 2);                     /* vm: +4 */                      \
            FENCE();                                                               \
            B_GLDS((K) + 2, BcurS == Ab0 ? Bb0 : Bb0); /* placeholder */           \
        } while (0)

    // (written out explicitly below instead of the macro above for clarity)
    #undef ITER_MAIN

    #define ITER(K, Acur, Anxt, Bcur, Bnxt, DO_ISSUE, WTAIL)                       \
        do {                                                                       \
            asm volatile("s_waitcnt vmcnt(8)" ::: "memory");  /* A(K+1) landed */  \
            SCHEDB();                                                              \
            COMPUTE(Acur, Bcur);                                                   \
            A_WRITE(Anxt);                                                         \
            SCHEDB(); BAR(); SCHEDB();        /* barrier A: done reading cur */    \
            if (DO_ISSUE) {                                                        \
                A_LOAD((K) + 2);              /* vm: B(K+1)[8]+A(K+2)[4] */        \
                FENCE();                                                           \
                B_GLDS((K) + 2, Bcur);        /* vm: +B(K+2)[8] = 20 */            \
            }                                                                      \
            asm volatile(WTAIL ::: "memory"); /* B(K+1) + A-writes done */         \
            SCHEDB(); BAR(); SCHEDB();        /* barrier B: stage K+1 published */ \
        } while (0)

    ITER(0, Ab0, Ab1, Bb0, Bb1, 1, "s_waitcnt vmcnt(12) lgkmcnt(0)");
    ITER(1, Ab1, Ab0, Bb1, Bb0, 1, "s_waitcnt vmcnt(12) lgkmcnt(0)");
    ITER(2, Ab0, Ab1, Bb0, Bb1, 1, "s_waitcnt vmcnt(12) lgkmcnt(0)");
    ITER(3, Ab1, Ab0, Bb1, Bb0, 1, "s_waitcnt vmcnt(12) lgkmcnt(0)");
    ITER(4, Ab0, Ab1, Bb0, Bb1, 1, "s_waitcnt vmcnt(12) lgkmcnt(0)");
    ITER(5, Ab1, Ab0, Bb1, Bb0, 1, "s_waitcnt vmcnt(12) lgkmcnt(0)");
    // K=6: no stage 8; drain B(7) (tail), publish stage 7
    ITER(6, Ab0, Ab1, Bb0, Bb1, 0, "s_waitcnt vmcnt(0) lgkmcnt(0)");
    // K=7: outstanding = 0, just compute
    COMPUTE(Ab1, Bb1);

    __syncthreads();   // seal K-loop before LDS reuse

    // --- epilogue: tanh(acc + proj1[b,d]) * v[d], reduce over d ---
    float p1v[8], vv[8];
    #pragma unroll
    for (int ni = 0; ni < 8; ++ni) {
        int d = wc * 128 + ni * 16 + llo;
        p1v[ni] = wsP1[b * 512 + d];
        vv[ni]  = vvec[d];
    }
    float part[16];
    #pragma unroll
    for (int mi = 0; mi < 4; ++mi)
        #pragma unroll
        for (int r = 0; r < 4; ++r) {
            float s = 0.f;
            #pragma unroll
            for (int ni = 0; ni < 8; ++ni)
                s += tanh_fast(acc[mi][ni][r] + p1v[ni]) * vv[ni];
            part[mi * 4 + r] = s;
        }
    // reduce across the 16-lane column group (lane bits 0..3)
    #pragma unroll
    for (int off = 1; off < 16; off <<= 1)
        #pragma unroll
        for (int i = 0; i < 16; ++i)
            part[i] += __shfl_xor(part[i], off, 64);

    float* red = (float*)lds;   // [4 wc][128 rows]
    if (llo == 0) {
        #pragma unroll
        for (int mi = 0; mi < 4; ++mi)
            #pragma unroll
            for (int r = 0; r < 4; ++r)
                red[wc * 128 + wr * 64 + mi * 16 + lhi * 4 + r] = part[mi * 4 + r];
    }
    __syncthreads();
    if (tid < 128) {
        float s = red[tid] + red[128 + tid] + red[256 + tid] + red[384 + tid];
        out[m0 + tid] = s;
    }
}

// ---------------------------------------------------------------------------
// Kernel 3: row softmax over S=4096, in place on out. 32 blocks x 256.
// ---------------------------------------------------------------------------
__global__ __launch_bounds__(256) void softmax_kernel(float* __restrict__ out) {
    __shared__ float wred[8];
    const int b = blockIdx.x, tid = threadIdx.x;
    float* row = out + (size_t)b * 4096;
    float vals[16];
    float lmax = -1e30f;
    #pragma unroll
    for (int i = 0; i < 16; ++i) {
        vals[i] = row[i * 256 + tid];
        lmax = fmaxf(lmax, vals[i]);
    }
    #pragma unroll
    for (int off = 32; off >= 1; off >>= 1)
        lmax = fmaxf(lmax, __shfl_xor(lmax, off, 64));
    if ((tid & 63) == 0) wred[tid >> 6] = lmax;
    __syncthreads();
    float gmax = fmaxf(fmaxf(wred[0], wred[1]), fmaxf(wred[2], wred[3]));
    float lsum = 0.f;
    #pragma unroll
    for (int i = 0; i < 16; ++i) {
        vals[i] = expf(vals[i] - gmax);
        lsum += vals[i];
    }
    #pragma unroll
    for (int off = 32; off >= 1; off >>= 1)
        lsum += __shfl_xor(lsum, off, 64);
    if ((tid & 63) == 0) wred[4 + (tid >> 6)] = lsum;
    __syncthreads();
    float inv = 1.f / (wred[4] + wred[5] + wred[6] + wred[7]);
    #pragma unroll
    for (int i = 0; i < 16; ++i)
        row[i * 256 + tid] = vals[i] * inv;
}

extern "C" void kernel_launch(void* const* d_in, const int* in_sizes, int n_in,
                              void* d_out, int out_size, void* d_ws, size_t ws_size,
                              hipStream_t stream) {
    const float* dh   = (const float*)d_in[0];   // (32, 512)
    const float* enc  = (const float*)d_in[1];   // (32, 4096, 512)
    const float* Wat  = (const float*)d_in[2];   // (512, 1024)
    const float* batt = (const float*)d_in[3];   // (512,)
    const float* vvec = (const float*)d_in[4];   // (512,)
    float* out = (float*)d_out;                  // (32, 4096)

    unsigned short* wsB = (unsigned short*)d_ws;               // 512 KB bf16 W_e
    float* wsP1 = (float*)((char*)d_ws + 524288);              // 64 KB proj1

    hipLaunchKernelGGL(prep_kernel, dim3(96), dim3(512), 0, stream,
                       dh, Wat, batt, wsB, wsP1);
    hipLaunchKernelGGL(fused_kernel, dim3(1024), dim3(512), 0, stream,
                       enc, wsB, wsP1, vvec, out);
    hipLaunchKernelGGL(softmax_kernel, dim3(32), dim3(256), 0, stream, out);
}